// Round 2
// baseline (487.603 us; speedup 1.0000x reference)
//
#include <hip/hip_runtime.h>
#include <math.h>

typedef _Float16 f16;
typedef _Float16 f16x8 __attribute__((ext_vector_type(8)));
typedef float f32x4 __attribute__((ext_vector_type(4)));

#define DIM 1024

enum { EPI_PHI_MASK = 0, EPI_ID_F16 = 1, EPI_ID_F32 = 2 };

__device__ __forceinline__ float phi_f(float x) {
  return x > 0.f ? x + 1.f : __expf(x);  // elu(x)+1
}

// ---------------- NT GEMM: C[m,n] = epi(sum_k A[m,k]*Bw[n,k] + bias[n]) ----------------
// A: [*,K] row-major (fp32 or f16), Bw: [N,K] row-major fp32 (converted in staging).
// A row index = m_base + blockIdx.y*128 + r ; C row index = blockIdx.y*128 + r (local).
template <int EPI, bool A_F32>
__global__ __launch_bounds__(256) void gemm_nt(const void* __restrict__ Aptr,
                                               const float* __restrict__ Bw,
                                               const float* __restrict__ bias,
                                               const int* __restrict__ mask,
                                               void* __restrict__ Cptr,
                                               int m_base) {
  __shared__ f16 As[128][64];
  __shared__ f16 Bs[128][64];
  const int tid = threadIdx.x;
  const int lane = tid & 63;
  const int l15 = lane & 15, l4 = lane >> 4;
  const int w = tid >> 6, wr = w >> 1, wc = w & 1;
  const int n0 = blockIdx.x * 128;
  const int c0 = blockIdx.y * 128;       // local C row base
  const int m0 = m_base + c0;            // global A row base

  f32x4 acc[4][4];
#pragma unroll
  for (int j = 0; j < 4; j++) {
    float bv = bias[n0 + wc * 64 + j * 16 + l15];
#pragma unroll
    for (int i = 0; i < 4; i++) acc[i][j] = (f32x4){bv, bv, bv, bv};
  }

  for (int kt = 0; kt < DIM; kt += 64) {
    __syncthreads();
    if constexpr (A_F32) {
      const float* A = (const float*)Aptr;
#pragma unroll
      for (int r = 0; r < 8; r++) {
        int e = r * 1024 + tid * 4;
        int row = e >> 6, col = e & 63;
        float4 v = *(const float4*)(A + (size_t)(m0 + row) * DIM + kt + col);
        union { f16 h[4]; uint2 u; } p;
        p.h[0] = (f16)v.x; p.h[1] = (f16)v.y; p.h[2] = (f16)v.z; p.h[3] = (f16)v.w;
        *(uint2*)&As[row][col] = p.u;
      }
    } else {
      const f16* A = (const f16*)Aptr;
#pragma unroll
      for (int r = 0; r < 4; r++) {
        int e = r * 2048 + tid * 8;
        int row = e >> 6, col = e & 63;
        *(uint4*)&As[row][col] = *(const uint4*)(A + (size_t)(m0 + row) * DIM + kt + col);
      }
    }
#pragma unroll
    for (int r = 0; r < 8; r++) {
      int e = r * 1024 + tid * 4;
      int row = e >> 6, col = e & 63;
      float4 v = *(const float4*)(Bw + (size_t)(n0 + row) * DIM + kt + col);
      union { f16 h[4]; uint2 u; } p;
      p.h[0] = (f16)v.x; p.h[1] = (f16)v.y; p.h[2] = (f16)v.z; p.h[3] = (f16)v.w;
      *(uint2*)&Bs[row][col] = p.u;
    }
    __syncthreads();
#pragma unroll
    for (int ks = 0; ks < 2; ks++) {
      f16x8 af[4], bfr[4];
#pragma unroll
      for (int i = 0; i < 4; i++)
        af[i] = *(f16x8*)&As[wr * 64 + i * 16 + l15][ks * 32 + l4 * 8];
#pragma unroll
      for (int j = 0; j < 4; j++)
        bfr[j] = *(f16x8*)&Bs[wc * 64 + j * 16 + l15][ks * 32 + l4 * 8];
#pragma unroll
      for (int i = 0; i < 4; i++)
#pragma unroll
        for (int j = 0; j < 4; j++)
          acc[i][j] = __builtin_amdgcn_mfma_f32_16x16x32_f16(af[i], bfr[j], acc[i][j], 0, 0, 0);
    }
  }

#pragma unroll
  for (int i = 0; i < 4; i++)
#pragma unroll
    for (int j = 0; j < 4; j++) {
      const int rl = wr * 64 + i * 16 + l4 * 4;  // local row base of fragment
      const int gn = n0 + wc * 64 + j * 16 + l15;
#pragma unroll
      for (int r = 0; r < 4; r++) {
        int row = rl + r;
        float x = acc[i][j][r];
        if (EPI == EPI_PHI_MASK) {
          x = phi_f(x);
          if (mask[m_base + c0 + row] == 0) x = 0.f;
          ((f16*)Cptr)[(size_t)(c0 + row) * DIM + gn] = (f16)x;
        } else if (EPI == EPI_ID_F16) {
          ((f16*)Cptr)[(size_t)(c0 + row) * DIM + gn] = (f16)x;
        } else {
          ((float*)Cptr)[(size_t)(c0 + row) * DIM + gn] = x;
        }
      }
    }
}

// ---------------- KV partial: pKV[bh,cy,d,e] = sum_{s in 512-chunk} K[s,d]*V[s,e] ----------------
// Kp/Vp hold LOCAL rows for batches {2*half, 2*half+1} (8192 rows).
__global__ __launch_bounds__(256) void kv_partial(const f16* __restrict__ Kp,
                                                  const f16* __restrict__ Vp,
                                                  float* __restrict__ pKV,
                                                  float* __restrict__ pKs,
                                                  int half) {
  const int bhl = blockIdx.x;            // 0..31
  const int cy = blockIdx.y;             // 0..7 chunks of 512 rows
  const int bloc = bhl >> 4;             // local batch 0/1
  const int h = bhl & 15;
  const int bh = (2 * half + bloc) * 16 + h;
  __shared__ f16 Ks[64][64];
  __shared__ f16 Vs[64][64];
  const int tid = threadIdx.x;
  const int d = tid & 63;
  const int eg = tid >> 6;
  float acc[16];
#pragma unroll
  for (int e = 0; e < 16; e++) acc[e] = 0.f;
  float ksacc = 0.f;
  const size_t rowbase = ((size_t)bloc * 4096 + (size_t)cy * 512) * DIM + h * 64;
  for (int sc = 0; sc < 8; sc++) {
    __syncthreads();
#pragma unroll
    for (int r = 0; r < 2; r++) {
      int e = r * 2048 + tid * 8;
      int row = e >> 6, col = e & 63;
      size_t g = rowbase + (size_t)(sc * 64 + row) * DIM + col;
      *(uint4*)&Ks[row][col] = *(const uint4*)(Kp + g);
      *(uint4*)&Vs[row][col] = *(const uint4*)(Vp + g);
    }
    __syncthreads();
    for (int s = 0; s < 64; s++) {
      float kd = (float)Ks[s][d];
      ksacc += kd;
      f16x8 v0 = *(f16x8*)&Vs[s][eg * 16];
      f16x8 v1 = *(f16x8*)&Vs[s][eg * 16 + 8];
#pragma unroll
      for (int q = 0; q < 8; q++) {
        acc[q] += kd * (float)v0[q];
        acc[8 + q] += kd * (float)v1[q];
      }
    }
  }
  const int ck = bh * 8 + cy;
  float* dst = pKV + ((size_t)ck * 64 + d) * 64 + eg * 16;
#pragma unroll
  for (int e = 0; e < 16; e++) dst[e] = acc[e];
  if (eg == 0) pKs[(size_t)ck * 64 + d] = ksacc;
}

// ---------------- reduce partials -> KVT (f16, [bh][e][d]) + Ksum(+eps) ----------------
__global__ __launch_bounds__(256) void kv_reduce(const float* __restrict__ pKV,
                                                 const float* __restrict__ pKs,
                                                 f16* __restrict__ KVT,
                                                 float* __restrict__ Ksum) {
  const int bh = blockIdx.x;
  const int tid = threadIdx.x;
  for (int cell = tid; cell < 4096; cell += 256) {
    float sum = 0.f;
#pragma unroll
    for (int c = 0; c < 8; c++) sum += pKV[(size_t)(bh * 8 + c) * 4096 + cell];
    int dd = cell >> 6, ee = cell & 63;
    KVT[(size_t)bh * 4096 + ee * 64 + dd] = (f16)sum;
  }
  if (tid < 64) {
    float s = 0.f;
#pragma unroll
    for (int c = 0; c < 8; c++) s += pKs[(size_t)(bh * 8 + c) * 64 + tid];
    Ksum[bh * 64 + tid] = s + 1e-6f;  // EPS folded in
  }
}

// ---------------- fused Q-projection -> phi -> Z -> V_new = Z * (phi(q) . KV) ----------------
// n-tile of 128 covers exactly 2 heads {nb*2, nb*2+1}.
__global__ __launch_bounds__(256) void gemm_q_vnew(const float* __restrict__ Aq,
                                                   const float* __restrict__ Wq,
                                                   const float* __restrict__ bq,
                                                   const f16* __restrict__ KVT,
                                                   const float* __restrict__ Ksum,
                                                   f16* __restrict__ Vnew) {
  __shared__ __attribute__((aligned(16))) char smem[32768 + 16384 + 1024 + 512];
  f16 (*As)[64] = (f16(*)[64])smem;                   // [128][64], phase 1
  f16 (*Bs)[64] = (f16(*)[64])(smem + 16384);         // [128][64], phase 1
  f16 (*Ph)[128] = (f16(*)[128])smem;                 // [128][128], overlays As+Bs
  f16* KVTs = (f16*)(smem + 32768);                   // [2][64][64]
  float* Zlds = (float*)(smem + 32768 + 16384);       // [2][128]
  float* KsumS = (float*)(smem + 32768 + 16384 + 1024);  // [128]

  const int tid = threadIdx.x;
  const int lane = tid & 63;
  const int l15 = lane & 15, l4 = lane >> 4;
  const int w = tid >> 6, wr = w >> 1, wc = w & 1;
  const int nb = blockIdx.x;      // 0..7
  const int n0 = nb * 128;
  const int m0 = blockIdx.y * 128;
  const int b = m0 >> 12;
  const int bh0 = b * 16 + nb * 2;

  // stage KV^T for the two heads + Ksum slice (non-overlaid LDS)
#pragma unroll
  for (int r = 0; r < 4; r++) {
    int e = r * 2048 + tid * 8;
    *(uint4*)(KVTs + e) = *(const uint4*)(KVT + (size_t)bh0 * 4096 + e);
  }
  if (tid < 128) KsumS[tid] = Ksum[bh0 * 64 + tid];

  // ---- phase 1: q = query @ Wq^T + bq ----
  f32x4 acc[4][4];
#pragma unroll
  for (int j = 0; j < 4; j++) {
    float bv = bq[n0 + wc * 64 + j * 16 + l15];
#pragma unroll
    for (int i = 0; i < 4; i++) acc[i][j] = (f32x4){bv, bv, bv, bv};
  }
  for (int kt = 0; kt < DIM; kt += 64) {
    __syncthreads();
#pragma unroll
    for (int r = 0; r < 8; r++) {
      int e = r * 1024 + tid * 4;
      int row = e >> 6, col = e & 63;
      float4 va = *(const float4*)(Aq + (size_t)(m0 + row) * DIM + kt + col);
      union { f16 h[4]; uint2 u; } pa;
      pa.h[0] = (f16)va.x; pa.h[1] = (f16)va.y; pa.h[2] = (f16)va.z; pa.h[3] = (f16)va.w;
      *(uint2*)&As[row][col] = pa.u;
      float4 vb = *(const float4*)(Wq + (size_t)(n0 + row) * DIM + kt + col);
      union { f16 h[4]; uint2 u; } pb;
      pb.h[0] = (f16)vb.x; pb.h[1] = (f16)vb.y; pb.h[2] = (f16)vb.z; pb.h[3] = (f16)vb.w;
      *(uint2*)&Bs[row][col] = pb.u;
    }
    __syncthreads();
#pragma unroll
    for (int ks = 0; ks < 2; ks++) {
      f16x8 af[4], bfr[4];
#pragma unroll
      for (int i = 0; i < 4; i++)
        af[i] = *(f16x8*)&As[wr * 64 + i * 16 + l15][ks * 32 + l4 * 8];
#pragma unroll
      for (int j = 0; j < 4; j++)
        bfr[j] = *(f16x8*)&Bs[wc * 64 + j * 16 + l15][ks * 32 + l4 * 8];
#pragma unroll
      for (int i = 0; i < 4; i++)
#pragma unroll
        for (int j = 0; j < 4; j++)
          acc[i][j] = __builtin_amdgcn_mfma_f32_16x16x32_f16(af[i], bfr[j], acc[i][j], 0, 0, 0);
    }
  }

  // ---- phi + stash to LDS (As/Bs dead) ----
  __syncthreads();
#pragma unroll
  for (int i = 0; i < 4; i++)
#pragma unroll
    for (int j = 0; j < 4; j++)
#pragma unroll
      for (int r = 0; r < 4; r++) {
        int row = wr * 64 + i * 16 + l4 * 4 + r;
        int col = wc * 64 + j * 16 + l15;
        Ph[row][col] = (f16)phi_f(acc[i][j][r]);
      }
  __syncthreads();

  // ---- Z[row] per head: 1 / (phi(q) . (Ksum+eps)) ----
  if (tid < 128) {
    float den0 = 0.f, den1 = 0.f;
    for (int c = 0; c < 64; c += 8) {
      f16x8 p0 = *(f16x8*)&Ph[tid][c];
      f16x8 p1 = *(f16x8*)&Ph[tid][64 + c];
#pragma unroll
      for (int q = 0; q < 8; q++) {
        den0 += (float)p0[q] * KsumS[c + q];
        den1 += (float)p1[q] * KsumS[64 + c + q];
      }
    }
    Zlds[tid] = 1.f / den0;
    Zlds[128 + tid] = 1.f / den1;
  }
  __syncthreads();

  // ---- phase 2: V_new = phi(q) @ KV (per head), scaled by Z ----
  f32x4 a2[4][4];
#pragma unroll
  for (int i = 0; i < 4; i++)
#pragma unroll
    for (int j = 0; j < 4; j++) a2[i][j] = (f32x4){0.f, 0.f, 0.f, 0.f};
#pragma unroll
  for (int ks = 0; ks < 2; ks++) {
    f16x8 af[4], bfr[4];
#pragma unroll
    for (int i = 0; i < 4; i++)
      af[i] = *(f16x8*)&Ph[wr * 64 + i * 16 + l15][wc * 64 + ks * 32 + l4 * 8];
#pragma unroll
    for (int j = 0; j < 4; j++)
      bfr[j] = *(f16x8*)&KVTs[wc * 4096 + (j * 16 + l15) * 64 + ks * 32 + l4 * 8];
#pragma unroll
    for (int i = 0; i < 4; i++)
#pragma unroll
      for (int j = 0; j < 4; j++)
        a2[i][j] = __builtin_amdgcn_mfma_f32_16x16x32_f16(af[i], bfr[j], a2[i][j], 0, 0, 0);
  }
#pragma unroll
  for (int i = 0; i < 4; i++)
#pragma unroll
    for (int j = 0; j < 4; j++)
#pragma unroll
      for (int r = 0; r < 4; r++) {
        int row = wr * 64 + i * 16 + l4 * 4 + r;
        float zv = Zlds[wc * 128 + row];
        int gn = n0 + wc * 64 + j * 16 + l15;
        Vnew[(size_t)(m0 + row) * DIM + gn] = (f16)(a2[i][j][r] * zv);
      }
}

extern "C" void kernel_launch(void* const* d_in, const int* in_sizes, int n_in,
                              void* d_out, int out_size, void* d_ws, size_t ws_size,
                              hipStream_t stream) {
  (void)in_sizes; (void)n_in; (void)out_size; (void)ws_size;
  const float* query = (const float*)d_in[0];
  const float* key = (const float*)d_in[1];
  const float* value = (const float*)d_in[2];
  const int* kmask = (const int*)d_in[3];
  const float* Wq = (const float*)d_in[4];
  const float* bq = (const float*)d_in[5];
  const float* Wk = (const float*)d_in[6];
  const float* bk = (const float*)d_in[7];
  const float* Wv = (const float*)d_in[8];
  const float* bv = (const float*)d_in[9];
  const float* Wo = (const float*)d_in[10];
  const float* bo = (const float*)d_in[11];

  // workspace layout (total ~40.7 MiB)
  char* ws = (char*)d_ws;
  f16* V = (f16*)ws;                                   // [16384][1024] f16 = 32 MiB (phase B)
  f16* P1 = (f16*)ws;                                  // 16 MiB (phase A: K half)
  f16* P2 = (f16*)(ws + ((size_t)16 << 20));           // 16 MiB (phase A: V half)
  float* pKV = (float*)(ws + ((size_t)32 << 20));      // 64*8*64*64 f32 = 8 MiB
  float* pKs = (float*)(ws + ((size_t)40 << 20));      // 64*8*64 f32 = 128 KiB
  f16* KVT = (f16*)(ws + ((size_t)40 << 20) + ((size_t)128 << 10));   // 512 KiB
  float* Ksum = (float*)(ws + ((size_t)40 << 20) + ((size_t)640 << 10));  // 16 KiB

  dim3 blk(256);
  dim3 ghalf(8, 64);  // 8 n-tiles x 64 m-tiles (8192 rows)
  for (int half = 0; half < 2; half++) {
    int mb = half * 8192;
    gemm_nt<EPI_PHI_MASK, true><<<ghalf, blk, 0, stream>>>(key, Wk, bk, kmask, P1, mb);
    gemm_nt<EPI_ID_F16, true><<<ghalf, blk, 0, stream>>>(value, Wv, bv, nullptr, P2, mb);
    kv_partial<<<dim3(32, 8), blk, 0, stream>>>(P1, P2, pKV, pKs, half);
  }
  kv_reduce<<<64, blk, 0, stream>>>(pKV, pKs, KVT, Ksum);
  gemm_q_vnew<<<dim3(8, 128), blk, 0, stream>>>(query, Wq, bq, KVT, Ksum, V);
  gemm_nt<EPI_ID_F32, false><<<dim3(8, 128), blk, 0, stream>>>(V, Wo, bo, nullptr, d_out, 0);
}